// Round 12
// baseline (629.271 us; speedup 1.0000x reference)
//
#include <hip/hip_runtime.h>
#include <math.h>

// MultiHeadedAttention  B=2, S=2048, D=1024, H=16, DH=64 (fp32 in/out)
// R11: single persistent kernel. Ledger across R1-R10 shows ~20us per
// serialized launch (~100us total) of inter-dispatch overhead. Fuse
// prep(wsplit+mask) -> qkv -> attn -> out into one 512-block dispatch with
// manual device-scope grid barriers (generation counter). Co-residency
// guaranteed: 64KB LDS + __launch_bounds__(256,2) => exactly 2 blocks/CU.
// Phase bodies byte-identical to R10.
// ws: Qbf@0 Kbf@8M Vt@16M mpk@32M Whi@33M ctxHi@41M ctxLo@49M barrier@58M

constexpr int Bc  = 2;
constexpr int Sc  = 2048;
constexpr int Dc  = 1024;
constexpr int Hc  = 16;
constexpr int DHc = 64;
constexpr int BSc = Bc * Sc;     // 4096

constexpr float LOG2E = 1.4426950408889634f;

typedef __bf16 bf16x8 __attribute__((ext_vector_type(8)));
typedef __bf16 bf16x4 __attribute__((ext_vector_type(4)));
typedef float  f32x4  __attribute__((ext_vector_type(4)));

#define GLDS16(gp, lp) __builtin_amdgcn_global_load_lds( \
    (const __attribute__((address_space(1))) void*)(gp), \
    (__attribute__((address_space(3))) void*)(lp), 16, 0, 0)

// ---------------------------------------------------------------------------
// Device-scope grid barrier (generation counter). All 512 blocks co-resident
// by construction (64KB LDS + VGPR<=256 => 2 blocks/CU exactly).
// ---------------------------------------------------------------------------
__device__ __forceinline__ void grid_sync(unsigned* cnt, unsigned* gen, unsigned nb)
{
    __syncthreads();
    if (threadIdx.x == 0) {
        __threadfence();   // make this block's writes device-visible
        const unsigned g = __hip_atomic_load(gen, __ATOMIC_RELAXED,
                                             __HIP_MEMORY_SCOPE_AGENT);
        const unsigned prev = __hip_atomic_fetch_add(cnt, 1u, __ATOMIC_ACQ_REL,
                                                     __HIP_MEMORY_SCOPE_AGENT);
        if (prev == nb - 1) {
            __hip_atomic_store(cnt, 0u, __ATOMIC_RELAXED,
                               __HIP_MEMORY_SCOPE_AGENT);
            __hip_atomic_fetch_add(gen, 1u, __ATOMIC_ACQ_REL,
                                   __HIP_MEMORY_SCOPE_AGENT);
        } else {
            while (__hip_atomic_load(gen, __ATOMIC_ACQUIRE,
                                     __HIP_MEMORY_SCOPE_AGENT) == g)
                __builtin_amdgcn_s_sleep(8);
        }
        __threadfence();
    }
    __syncthreads();
}

// ---------------------------------------------------------------------------
// Pipelined single-pass K-sweep, M-tile 128 (R10 sweep128p, unchanged).
// ---------------------------------------------------------------------------
__device__ __forceinline__ void sweep128p(const float* __restrict__ A,
                                          const __bf16* __restrict__ Wh,
                                          char* AsB, char* WsB,
                                          int gm0, int gn0, f32x4 acc[4][4])
{
    const int tid  = threadIdx.x;
    const int w    = tid >> 6;
    const int lane = tid & 63;
    const int cc   = lane & 15;
    const int g    = lane >> 4;
    const int wm   = (w & 1) * 64;
    const int wn   = (w >> 1) * 64;

    int wrow[4], wchk[4];
#pragma unroll
    for (int r = 0; r < 4; ++r) {
        const int L = r * 256 + tid;
        wrow[r] = L >> 3;
        wchk[r] = (L & 7) ^ (wrow[r] & 7);
    }

    float4 av[8];
#pragma unroll
    for (int r = 0; r < 4; ++r)
        GLDS16(Wh + (size_t)(gn0 + wrow[r]) * Dc + wchk[r] * 8,
               WsB + (r * 256 + tid) * 16);
#pragma unroll
    for (int i = 0; i < 8; ++i) {
        const int Lq = i * 256 + tid;
        av[i] = *(const float4*)&A[(size_t)(gm0 + (Lq >> 4)) * Dc + (Lq & 15) * 4];
    }
#pragma unroll
    for (int i = 0; i < 8; ++i) {
        const int Lq = i * 256 + tid;
        const int ar = Lq >> 4, aq = Lq & 15;
        const int off = ar * 128 + ((((aq >> 1) ^ (ar & 7)) << 4) | ((aq & 1) << 3));
        bf16x4 hv;
        hv[0] = (__bf16)av[i].x; hv[1] = (__bf16)av[i].y;
        hv[2] = (__bf16)av[i].z; hv[3] = (__bf16)av[i].w;
        *(bf16x4*)(AsB + off) = hv;
    }

    for (int it = 0; it < Dc / 64; ++it) {
        const char* As = AsB + (it & 1) * 16384;
        const char* Ws = WsB + (it & 1) * 16384;
        __syncthreads();

        const bool more = (it + 1 < Dc / 64);
        if (more) {
            const int kn = (it + 1) * 64;
            char* Wn = WsB + ((it + 1) & 1) * 16384;
#pragma unroll
            for (int r = 0; r < 4; ++r)
                GLDS16(Wh + (size_t)(gn0 + wrow[r]) * Dc + kn + wchk[r] * 8,
                       Wn + (r * 256 + tid) * 16);
#pragma unroll
            for (int i = 0; i < 8; ++i) {
                const int Lq = i * 256 + tid;
                av[i] = *(const float4*)
                    &A[(size_t)(gm0 + (Lq >> 4)) * Dc + kn + (Lq & 15) * 4];
            }
        }

#pragma unroll
        for (int kk = 0; kk < 2; ++kk) {
            const int cb4 = (kk * 4 + g) << 4;
            bf16x8 af[4], bfr[4];
#pragma unroll
            for (int mt = 0; mt < 4; ++mt) {
                const int row = wm + mt * 16 + cc;
                af[mt] = *(const bf16x8*)(As + row * 128 + (cb4 ^ ((row & 7) << 4)));
            }
#pragma unroll
            for (int nt = 0; nt < 4; ++nt) {
                const int row = wn + nt * 16 + cc;
                bfr[nt] = *(const bf16x8*)(Ws + row * 128 + (cb4 ^ ((row & 7) << 4)));
            }
#pragma unroll
            for (int mt = 0; mt < 4; ++mt)
#pragma unroll
                for (int nt = 0; nt < 4; ++nt)
                    acc[mt][nt] = __builtin_amdgcn_mfma_f32_16x16x32_bf16(
                        af[mt], bfr[nt], acc[mt][nt], 0, 0, 0);
        }

        if (more) {
            char* An = AsB + ((it + 1) & 1) * 16384;
#pragma unroll
            for (int i = 0; i < 8; ++i) {
                const int Lq = i * 256 + tid;
                const int ar = Lq >> 4, aq = Lq & 15;
                const int off = ar * 128 +
                                ((((aq >> 1) ^ (ar & 7)) << 4) | ((aq & 1) << 3));
                bf16x4 hv;
                hv[0] = (__bf16)av[i].x; hv[1] = (__bf16)av[i].y;
                hv[2] = (__bf16)av[i].z; hv[3] = (__bf16)av[i].w;
                *(bf16x4*)(An + off) = hv;
            }
        }
    }
}

// ---------------------------------------------------------------------------
// Pipelined hi/lo K-sweep, M64 (R10 sweep64p, unchanged).
// ---------------------------------------------------------------------------
__device__ __forceinline__ void sweep64p(const __bf16* __restrict__ Ahi,
                                         const __bf16* __restrict__ Alo,
                                         const __bf16* __restrict__ Wh,
                                         char* WsB, char* AhB, char* AlB,
                                         int gm0, int gn0, f32x4 acc[2][4])
{
    const int tid  = threadIdx.x;
    const int w    = tid >> 6;
    const int lane = tid & 63;
    const int cc   = lane & 15;
    const int g    = lane >> 4;
    const int wm   = (w & 1) * 32;
    const int wn   = (w >> 1) * 64;

    int wrow[4], wchk[4];
#pragma unroll
    for (int r = 0; r < 4; ++r) {
        const int L = r * 256 + tid;
        wrow[r] = L >> 3;
        wchk[r] = (L & 7) ^ (wrow[r] & 7);
    }
    int arow[2], achk[2];
#pragma unroll
    for (int r = 0; r < 2; ++r) {
        const int L = r * 256 + tid;
        arow[r] = L >> 3;
        achk[r] = (L & 7) ^ (arow[r] & 7);
    }

#pragma unroll
    for (int r = 0; r < 4; ++r)
        GLDS16(Wh + (size_t)(gn0 + wrow[r]) * Dc + wchk[r] * 8,
               WsB + (r * 256 + tid) * 16);
#pragma unroll
    for (int r = 0; r < 2; ++r) {
        GLDS16(Ahi + (size_t)(gm0 + arow[r]) * Dc + achk[r] * 8,
               AhB + (r * 256 + tid) * 16);
        GLDS16(Alo + (size_t)(gm0 + arow[r]) * Dc + achk[r] * 8,
               AlB + (r * 256 + tid) * 16);
    }

    for (int it = 0; it < Dc / 64; ++it) {
        const char* Ws = WsB + (it & 1) * 16384;
        const char* Ah = AhB + (it & 1) * 8192;
        const char* Al = AlB + (it & 1) * 8192;
        __syncthreads();

        if (it + 1 < Dc / 64) {
            const int kn = (it + 1) * 64;
            char* Wn = WsB + ((it + 1) & 1) * 16384;
            char* Hn = AhB + ((it + 1) & 1) * 8192;
            char* Ln = AlB + ((it + 1) & 1) * 8192;
#pragma unroll
            for (int r = 0; r < 4; ++r)
                GLDS16(Wh + (size_t)(gn0 + wrow[r]) * Dc + kn + wchk[r] * 8,
                       Wn + (r * 256 + tid) * 16);
#pragma unroll
            for (int r = 0; r < 2; ++r) {
                GLDS16(Ahi + (size_t)(gm0 + arow[r]) * Dc + kn + achk[r] * 8,
                       Hn + (r * 256 + tid) * 16);
                GLDS16(Alo + (size_t)(gm0 + arow[r]) * Dc + kn + achk[r] * 8,
                       Ln + (r * 256 + tid) * 16);
            }
        }

#pragma unroll
        for (int kk = 0; kk < 2; ++kk) {
            const int cb4 = (kk * 4 + g) << 4;
            bf16x8 ahi[2], alo[2], bfr[4];
#pragma unroll
            for (int mt = 0; mt < 2; ++mt) {
                const int row = wm + mt * 16 + cc;
                const int off = row * 128 + (cb4 ^ ((row & 7) << 4));
                ahi[mt] = *(const bf16x8*)(Ah + off);
                alo[mt] = *(const bf16x8*)(Al + off);
            }
#pragma unroll
            for (int nt = 0; nt < 4; ++nt) {
                const int row = wn + nt * 16 + cc;
                bfr[nt] = *(const bf16x8*)(Ws + row * 128 + (cb4 ^ ((row & 7) << 4)));
            }
#pragma unroll
            for (int mt = 0; mt < 2; ++mt)
#pragma unroll
                for (int nt = 0; nt < 4; ++nt) {
                    acc[mt][nt] = __builtin_amdgcn_mfma_f32_16x16x32_bf16(
                        ahi[mt], bfr[nt], acc[mt][nt], 0, 0, 0);
                    acc[mt][nt] = __builtin_amdgcn_mfma_f32_16x16x32_bf16(
                        alo[mt], bfr[nt], acc[mt][nt], 0, 0, 0);
                }
        }
    }
}

// ---------------------------------------------------------------------------
// Phase bodies (R10 kernels as device functions)
// ---------------------------------------------------------------------------
__device__ void phase_qkv(int bx, int by, int bz, char* smem,
                          const float* query, const float* key, const float* value,
                          const __bf16* Whi, const float* bq, const float* bk,
                          const float* bv,
                          __bf16* Qo, __bf16* Ko, __bf16* Vt)
{
    const float* A    = (bz == 0) ? query : (bz == 1) ? key : value;
    const float* bias = (bz == 0) ? bq    : (bz == 1) ? bk  : bv;
    const float scale = (bz == 0) ? 0.125f * LOG2E : 1.0f;
    const __bf16* Wh  = Whi + (size_t)bz * Dc * Dc;

    const int gm0 = bx * 128;
    const int gn0 = by * 128;

    f32x4 acc[4][4];
#pragma unroll
    for (int mt = 0; mt < 4; ++mt)
#pragma unroll
        for (int nt = 0; nt < 4; ++nt) acc[mt][nt] = {0.f, 0.f, 0.f, 0.f};

    sweep128p(A, Wh, smem, smem + 32768, gm0, gn0, acc);

    const int tid = threadIdx.x;
    const int w = tid >> 6, lane = tid & 63;
    const int cc = lane & 15, g = lane >> 4;
    const int wm = (w & 1) * 64, wn = (w >> 1) * 64;

    float bias4[4];
#pragma unroll
    for (int nt = 0; nt < 4; ++nt) bias4[nt] = bias[gn0 + wn + nt * 16 + cc];

    if (bz == 2) {
#pragma unroll
        for (int mt = 0; mt < 4; ++mt)
#pragma unroll
            for (int nt = 0; nt < 4; ++nt) {
                const int col = gn0 + wn + nt * 16 + cc;
                const int h = col >> 6, dh = col & 63;
                const int row0 = gm0 + wm + mt * 16 + g * 4;
                const int b = row0 >> 11, s0 = row0 & 2047;
                bf16x4 vv;
#pragma unroll
                for (int reg = 0; reg < 4; ++reg)
                    vv[reg] = (__bf16)(acc[mt][nt][reg] + bias4[nt]);
                *(bf16x4*)&Vt[(((size_t)(b * Hc + h)) * DHc + dh) * Sc + s0] = vv;
            }
    } else {
        __bf16* O = (bz == 0) ? Qo : Ko;
#pragma unroll
        for (int mt = 0; mt < 4; ++mt)
#pragma unroll
            for (int nt = 0; nt < 4; ++nt) {
                const int col = gn0 + wn + nt * 16 + cc;
                const int h = col >> 6, dh = col & 63;
#pragma unroll
                for (int reg = 0; reg < 4; ++reg) {
                    const int row = gm0 + wm + mt * 16 + g * 4 + reg;
                    const int b = row >> 11, s = row & 2047;
                    O[(((size_t)(b * Hc + h)) * Sc + s) * DHc + dh] =
                        (__bf16)((acc[mt][nt][reg] + bias4[nt]) * scale);
                }
            }
    }
}

__device__ void phase_attn(int bx, int by, char* smem,
                           const __bf16* Q, const __bf16* K, const __bf16* Vt,
                           const unsigned long long* mp,
                           __bf16* ctxHi, __bf16* ctxLo)
{
    const int tid  = threadIdx.x;
    const int w    = tid >> 6;
    const int lane = tid & 63;
    const int cc   = lane & 15;
    const int g    = lane >> 4;
    const int bh   = by;
    const int b    = bh >> 4;
    const int h    = bh & 15;
    const int qw   = bx * 128 + w * 32;

    const __bf16* Qb  = Q  + (size_t)bh * Sc * DHc;
    const __bf16* Kb  = K  + (size_t)bh * Sc * DHc;
    const __bf16* Vtb = Vt + (size_t)bh * DHc * Sc;

    char* Pw = smem + 32768 + w * 2048;

    bf16x8 qa[2][2];
#pragma unroll
    for (int mt = 0; mt < 2; ++mt) {
        qa[mt][0] = *(const bf16x8*)&Qb[(size_t)(qw + mt * 16 + cc) * DHc + g * 8];
        qa[mt][1] = *(const bf16x8*)&Qb[(size_t)(qw + mt * 16 + cc) * DHc + 32 + g * 8];
    }

    f32x4 o[2][4] = {};
    float l[2][4] = {};

    const int ci[2] = {tid, 256 + tid};
    int  rowi[2], ski[2];
#pragma unroll
    for (int i = 0; i < 2; ++i) {
        rowi[i] = ci[i] >> 3;
        const int sl = ci[i] & 7;
        ski[i] = sl ^ (rowi[i] & 7);
    }

#pragma unroll
    for (int i = 0; i < 2; ++i) {
        GLDS16(Kb + (size_t)rowi[i] * DHc + ski[i] * 8, smem + ci[i] * 16);
        GLDS16(Vtb + (size_t)rowi[i] * Sc + ski[i] * 8, smem + 8192 + ci[i] * 16);
    }

    for (int it = 0; it < 32; ++it) {
        const int k0 = it * 64;
        char* Ks = smem + (it & 1) * 16384;
        char* Vs = Ks + 8192;

        __syncthreads();

        if (it + 1 < 32) {
            char* Kn = smem + ((it + 1) & 1) * 16384;
            const int kn = k0 + 64;
#pragma unroll
            for (int i = 0; i < 2; ++i) {
                GLDS16(Kb + (size_t)(kn + rowi[i]) * DHc + ski[i] * 8,
                       Kn + ci[i] * 16);
                GLDS16(Vtb + (size_t)rowi[i] * Sc + kn + ski[i] * 8,
                       Kn + 8192 + ci[i] * 16);
            }
        }

        unsigned long long mw[2][4];
#pragma unroll
        for (int mt = 0; mt < 2; ++mt)
#pragma unroll
            for (int r = 0; r < 4; ++r)
                mw[mt][r] = mp[(size_t)(b * Sc + qw + mt * 16 + g * 4 + r) * (Sc / 64)
                               + (k0 >> 6)];

        f32x4 sc[2][4];
#pragma unroll
        for (int nt = 0; nt < 4; ++nt) {
            const int row = nt * 16 + cc;
            const int rx  = (row & 7) << 4;
            const bf16x8 kb0 = *(const bf16x8*)(Ks + row * 128 + ((g << 4) ^ rx));
            const bf16x8 kb1 = *(const bf16x8*)(Ks + row * 128 + ((64 + (g << 4)) ^ rx));
            f32x4 z0 = {-24.f, -24.f, -24.f, -24.f};
            z0 = __builtin_amdgcn_mfma_f32_16x16x32_bf16(qa[0][0], kb0, z0, 0, 0, 0);
            z0 = __builtin_amdgcn_mfma_f32_16x16x32_bf16(qa[0][1], kb1, z0, 0, 0, 0);
            sc[0][nt] = z0;
            f32x4 z1 = {-24.f, -24.f, -24.f, -24.f};
            z1 = __builtin_amdgcn_mfma_f32_16x16x32_bf16(qa[1][0], kb0, z1, 0, 0, 0);
            z1 = __builtin_amdgcn_mfma_f32_16x16x32_bf16(qa[1][1], kb1, z1, 0, 0, 0);
            sc[1][nt] = z1;
        }

        bf16x8 pa[2][2];
#pragma unroll
        for (int mt = 0; mt < 2; ++mt) {
            unsigned mlo[4], mhi[4];
#pragma unroll
            for (int r = 0; r < 4; ++r) {
                const unsigned long long sh = mw[mt][r] >> cc;
                mlo[r] = (unsigned)sh;
                mhi[r] = (unsigned)(sh >> 32);
            }
#pragma unroll
            for (int nt = 0; nt < 4; ++nt)
#pragma unroll
                for (int r = 0; r < 4; ++r) {
                    float p = __builtin_amdgcn_exp2f(sc[mt][nt][r]);
                    const unsigned bit =
                        (nt == 0) ? (mlo[r] & 1u) :
                        (nt == 1) ? (mlo[r] & 0x10000u) :
                        (nt == 2) ? (mhi[r] & 1u) : (mhi[r] & 0x10000u);
                    p = bit ? 0.f : p;
                    l[mt][r] += p;
                    *(__bf16*)(Pw + (g * 4 + r) * 128 +
                               (((nt ^ g) << 5) | (cc << 1))) = (__bf16)p;
                }
            const int sw = (cc >> 2) << 5;
            pa[mt][0] = *(const bf16x8*)(Pw + cc * 128 + ((g * 16) ^ sw));
            pa[mt][1] = *(const bf16x8*)(Pw + cc * 128 + ((64 + g * 16) ^ sw));
        }

#pragma unroll
        for (int nt = 0; nt < 4; ++nt) {
            const int row = nt * 16 + cc;
            const int rx  = (row & 7) << 4;
            const bf16x8 vb0 = *(const bf16x8*)(Vs + row * 128 + ((g << 4) ^ rx));
            const bf16x8 vb1 = *(const bf16x8*)(Vs + row * 128 + ((64 + (g << 4)) ^ rx));
            o[0][nt] = __builtin_amdgcn_mfma_f32_16x16x32_bf16(pa[0][0], vb0, o[0][nt], 0, 0, 0);
            o[0][nt] = __builtin_amdgcn_mfma_f32_16x16x32_bf16(pa[0][1], vb1, o[0][nt], 0, 0, 0);
            o[1][nt] = __builtin_amdgcn_mfma_f32_16x16x32_bf16(pa[1][0], vb0, o[1][nt], 0, 0, 0);
            o[1][nt] = __builtin_amdgcn_mfma_f32_16x16x32_bf16(pa[1][1], vb1, o[1][nt], 0, 0, 0);
        }
    }

#pragma unroll
    for (int off = 1; off < 16; off <<= 1)
#pragma unroll
        for (int mt = 0; mt < 2; ++mt)
#pragma unroll
            for (int r = 0; r < 4; ++r)
                l[mt][r] += __shfl_xor(l[mt][r], off, 16);

#pragma unroll
    for (int mt = 0; mt < 2; ++mt)
#pragma unroll
        for (int r = 0; r < 4; ++r) {
            const float inv = 1.0f / l[mt][r];
            const int q = qw + mt * 16 + g * 4 + r;
#pragma unroll
            for (int nt = 0; nt < 4; ++nt) {
                const size_t idx = ((size_t)b * Sc + q) * Dc + h * 64 + nt * 16 + cc;
                const float v = o[mt][nt][r] * inv;
                const __bf16 hi = (__bf16)v;
                ctxHi[idx] = hi;
                ctxLo[idx] = (__bf16)(v - (float)hi);
            }
        }
}

__device__ void phase_out(int bx, int by, char* smem,
                          const __bf16* ctxHi, const __bf16* ctxLo,
                          const __bf16* Wohi, const float* bo, float* out)
{
    const int gm0 = bx * 64;
    const int gn0 = by * 128;

    f32x4 acc[2][4];
#pragma unroll
    for (int mt = 0; mt < 2; ++mt)
#pragma unroll
        for (int nt = 0; nt < 4; ++nt) acc[mt][nt] = {0.f, 0.f, 0.f, 0.f};

    sweep64p(ctxHi, ctxLo, Wohi, smem, smem + 32768, smem + 49152, gm0, gn0, acc);

    const int tid = threadIdx.x;
    const int w = tid >> 6, lane = tid & 63;
    const int cc = lane & 15, g = lane >> 4;
    const int wm = (w & 1) * 32, wn = (w >> 1) * 64;

    float bias4[4];
#pragma unroll
    for (int nt = 0; nt < 4; ++nt) bias4[nt] = bo[gn0 + wn + nt * 16 + cc];

#pragma unroll
    for (int mt = 0; mt < 2; ++mt)
#pragma unroll
        for (int nt = 0; nt < 4; ++nt) {
            const int col = gn0 + wn + nt * 16 + cc;
#pragma unroll
            for (int reg = 0; reg < 4; ++reg) {
                const int row = gm0 + wm + mt * 16 + g * 4 + reg;
                out[(size_t)row * Dc + col] = acc[mt][nt][reg] + bias4[nt];
            }
        }
}

// ---------------------------------------------------------------------------
// The fused persistent kernel. Grid = 512 x 256. LDS 64KB (union of phases).
// ---------------------------------------------------------------------------
__global__ __launch_bounds__(256, 2)
void fused_mha(const float* __restrict__ query, const float* __restrict__ key,
               const float* __restrict__ value, const int* __restrict__ mask,
               const float* __restrict__ Wq, const float* __restrict__ bq,
               const float* __restrict__ Wk, const float* __restrict__ bk,
               const float* __restrict__ Wv, const float* __restrict__ bv,
               const float* __restrict__ Wo, const float* __restrict__ bo,
               __bf16* __restrict__ Qbf, __bf16* __restrict__ Kbf,
               __bf16* __restrict__ Vt, unsigned long long* __restrict__ mpk,
               __bf16* __restrict__ Whi, __bf16* __restrict__ ctxHi,
               __bf16* __restrict__ ctxLo, float* __restrict__ out,
               unsigned* __restrict__ bar)
{
    __shared__ __align__(16) char smem[65536];
    const unsigned nb = gridDim.x;
    const int bid = blockIdx.x;
    const int tid = threadIdx.x;
    unsigned* cnt = bar;
    unsigned* gen = bar + 16;   // separate cachelines

    // ---- phase 0: wsplit + mask_pack ----
    {
        const float* src[4] = {Wq, Wk, Wv, Wo};
        for (int t = bid; t < 4096; t += nb) {
            const int x = t & 1023, z = t >> 10;
            const size_t idx = ((size_t)x * 256 + tid) * 4;
            const float4 v = *(const float4*)&src[z][idx];
            bf16x4 o;
            o[0] = (__bf16)v.x; o[1] = (__bf16)v.y;
            o[2] = (__bf16)v.z; o[3] = (__bf16)v.w;
            *(bf16x4*)&Whi[(size_t)z * Dc * Dc + idx] = o;
        }
        const int lane = tid & 63;
        for (int t = bid; t < 8192; t += nb) {
            const size_t waveBase = ((size_t)t * 4 + (tid >> 6)) * 256;
            unsigned long long b0 = __ballot(mask[waveBase + lane]       != 0);
            unsigned long long b1 = __ballot(mask[waveBase + 64 + lane]  != 0);
            unsigned long long b2 = __ballot(mask[waveBase + 128 + lane] != 0);
            unsigned long long b3 = __ballot(mask[waveBase + 192 + lane] != 0);
            if (lane == 0) {
                unsigned long long* dst = mpk + (waveBase >> 6);
                dst[0] = b0; dst[1] = b1; dst[2] = b2; dst[3] = b3;
            }
        }
    }
    grid_sync(cnt, gen, nb);

    // ---- phase 1: qkv ----
    for (int t = bid; t < 768; t += nb)
        phase_qkv(t & 31, (t >> 5) & 7, t >> 8, smem,
                  query, key, value, Whi, bq, bk, bv, Qbf, Kbf, Vt);
    grid_sync(cnt, gen, nb);

    // ---- phase 2: attention ----
    phase_attn(bid & 15, bid >> 4, smem, Qbf, Kbf, Vt, mpk, ctxHi, ctxLo);
    grid_sync(cnt, gen, nb);

    // ---- phase 3: output projection ----
    phase_out(bid & 63, bid >> 6, smem, ctxHi, ctxLo,
              Whi + (size_t)3 * Dc * Dc, bo, out);
}

extern "C" void kernel_launch(void* const* d_in, const int* in_sizes, int n_in,
                              void* d_out, int out_size, void* d_ws, size_t ws_size,
                              hipStream_t stream)
{
    const float* key   = (const float*)d_in[0];
    const float* value = (const float*)d_in[1];
    const float* query = (const float*)d_in[2];
    const int*   mask  = (const int*)  d_in[3];
    const float* Wq    = (const float*)d_in[4];
    const float* bq    = (const float*)d_in[5];
    const float* Wk    = (const float*)d_in[6];
    const float* bk    = (const float*)d_in[7];
    const float* Wv    = (const float*)d_in[8];
    const float* bv    = (const float*)d_in[9];
    const float* Wo    = (const float*)d_in[10];
    const float* bo    = (const float*)d_in[11];
    float* out = (float*)d_out;

    char* wsb = (char*)d_ws;
    __bf16* Qbf   = (__bf16*)(wsb);
    __bf16* Kbf   = (__bf16*)(wsb + ((size_t)8  << 20));
    __bf16* Vt    = (__bf16*)(wsb + ((size_t)16 << 20));
    unsigned long long* mpk = (unsigned long long*)(wsb + ((size_t)32 << 20));
    __bf16* Whi   = (__bf16*)(wsb + ((size_t)33 << 20));
    __bf16* ctxHi = (__bf16*)(wsb + ((size_t)41 << 20));
    __bf16* ctxLo = (__bf16*)(wsb + ((size_t)49 << 20));
    unsigned* bar = (unsigned*)(wsb + ((size_t)58 << 20));

    // zero the barrier counters (ws is re-poisoned 0xAA before every call)
    hipMemsetAsync(bar, 0, 128, stream);

    fused_mha<<<512, 256, 0, stream>>>(query, key, value, mask,
                                       Wq, bq, Wk, bk, Wv, bv, Wo, bo,
                                       Qbf, Kbf, Vt, mpk, Whi,
                                       ctxHi, ctxLo, out, bar);
}